// Round 1
// baseline (139.530 us; speedup 1.0000x reference)
//
#include <hip/hip_runtime.h>
#include <math.h>

#define N_ROWS 1048576
#define C_CLS 10
#define D_DIM 64

// ws layout (doubles): [0..9] seg_reg, [10..19] seg_ce, [20..29] counts
__global__ __launch_bounds__(256) void aux_main(
    const int* __restrict__ yhat,
    const float* __restrict__ yg,
    const float* __restrict__ u_zg,
    double* __restrict__ ws)
{
    __shared__ float s_reg[C_CLS];
    __shared__ float s_ce[C_CLS];
    __shared__ float s_cnt[C_CLS];
    const int tid = threadIdx.x;
    if (tid < C_CLS) { s_reg[tid] = 0.f; s_ce[tid] = 0.f; s_cnt[tid] = 0.f; }
    __syncthreads();

    const int gtid = blockIdx.x * blockDim.x + tid;
    const int nthreads = gridDim.x * blockDim.x;
    const int lane = tid & 63;
    const int gwave = gtid >> 6;
    const int nwaves = nthreads >> 6;
    const float INV = 1.41421356237f;  // 1/(0.5*sqrt(2)) = sqrt(2)

    // ---- Phase A: u_zg erf regularizer; one wave handles 4 rows per iter ----
    // 4 rows = 256 floats = 64 float4; lane l covers floats [4l,4l+4) of the
    // 4-row group -> row sub-index = l>>4; 16-lane xor-tree reduces per row.
    const float4* __restrict__ u4 = (const float4*)u_zg;
    for (int g = gwave; g < (N_ROWS / 4); g += nwaves) {
        float4 v = u4[(size_t)g * 64 + lane];
        float t = 0.5f * erfcf((-0.5f - v.x) * INV)
                + 0.5f * erfcf((-0.5f - v.y) * INV)
                + 0.5f * erfcf((-0.5f - v.z) * INV)
                + 0.5f * erfcf((-0.5f - v.w) * INV);
        t += __shfl_xor(t, 1);
        t += __shfl_xor(t, 2);
        t += __shfl_xor(t, 4);
        t += __shfl_xor(t, 8);
        if ((lane & 15) == 0) {
            int row = g * 4 + (lane >> 4);
            atomicAdd(&s_reg[yhat[row]], t);
        }
    }

    // ---- Phase B: per-row cross entropy (10 classes, 40B rows, float2 loads) ----
    for (int row = gtid; row < N_ROWS; row += nthreads) {
        const float* __restrict__ yr = yg + (size_t)row * C_CLS;
        float2 a0 = *(const float2*)(yr + 0);
        float2 a1 = *(const float2*)(yr + 2);
        float2 a2 = *(const float2*)(yr + 4);
        float2 a3 = *(const float2*)(yr + 6);
        float2 a4 = *(const float2*)(yr + 8);
        float m = fmaxf(fmaxf(fmaxf(a0.x, a0.y), fmaxf(a1.x, a1.y)),
                 fmaxf(fmaxf(fmaxf(a2.x, a2.y), fmaxf(a3.x, a3.y)),
                       fmaxf(a4.x, a4.y)));
        float s = expf(a0.x - m) + expf(a0.y - m)
                + expf(a1.x - m) + expf(a1.y - m)
                + expf(a2.x - m) + expf(a2.y - m)
                + expf(a3.x - m) + expf(a3.y - m)
                + expf(a4.x - m) + expf(a4.y - m);
        float lse = m + logf(s);
        int c = yhat[row];
        float ce = lse - yr[c];   // reload y[row,c]; L1 hit
        atomicAdd(&s_ce[c], ce);
        atomicAdd(&s_cnt[c], 1.0f);
    }

    __syncthreads();
    if (tid < C_CLS) {
        atomicAdd(&ws[tid],          (double)s_reg[tid]);
        atomicAdd(&ws[C_CLS + tid],  (double)s_ce[tid]);
        atomicAdd(&ws[2*C_CLS + tid],(double)s_cnt[tid]);
    }
}

__global__ void aux_final(const double* __restrict__ ws,
                          const float* __restrict__ lmbd,
                          float* __restrict__ out)
{
    if (threadIdx.x == 0 && blockIdx.x == 0) {
        double sreg = 0.0, sce = 0.0, nuniq = 0.0;
        for (int k = 0; k < C_CLS; ++k) {
            double cnt = ws[2*C_CLS + k];
            if (cnt > 0.0) {
                sreg += ws[k] / (cnt * (double)D_DIM);
                sce  += ws[C_CLS + k] / cnt;
                nuniq += 1.0;
            }
        }
        double reg_loss = sreg / nuniq;
        double aux_loss = sce / nuniq;
        out[0] = (float)(aux_loss + (double)lmbd[0] * reg_loss);
    }
}

extern "C" void kernel_launch(void* const* d_in, const int* in_sizes, int n_in,
                              void* d_out, int out_size, void* d_ws, size_t ws_size,
                              hipStream_t stream) {
    const int*   yhat = (const int*)d_in[0];
    const float* yg   = (const float*)d_in[1];
    const float* u_zg = (const float*)d_in[2];
    const float* lmbd = (const float*)d_in[3];
    float* out = (float*)d_out;
    double* ws = (double*)d_ws;

    hipMemsetAsync(ws, 0, 3 * C_CLS * sizeof(double), stream);
    aux_main<<<2048, 256, 0, stream>>>(yhat, yg, u_zg, ws);
    aux_final<<<1, 64, 0, stream>>>(ws, lmbd, out);
}

// Round 2
// 125.701 us; speedup vs baseline: 1.1100x; 1.1100x over previous
//
#include <hip/hip_runtime.h>
#include <math.h>

#define N_ROWS 1048576
#define C_CLS 10
#define D_DIM 64

// f(u) = 0.5 - 0.5*erf((-0.5-u)*sqrt(2)) = 0.5 + 0.5*erf(x), x = (u+0.5)*sqrt(2)
// A&S 7.1.26 erfc approx: max abs err 1.5e-7 (final-loss error ~1e-8, threshold 5.6e-2)
__device__ __forceinline__ float f_reg(float u) {
    float x  = fmaf(u, 1.41421356237f, 0.70710678118f);
    float ax = fabsf(x);
    float t  = __builtin_amdgcn_rcpf(fmaf(0.3275911f, ax, 1.0f));   // v_rcp_f32
    float p  = fmaf(fmaf(fmaf(fmaf(1.061405429f, t, -1.453152027f),
                              t, 1.421413741f),
                         t, -0.284496736f),
                    t, 0.254829592f);
    float e  = __expf(-ax * ax);                                     // v_exp_f32
    float h  = 0.5f * p * t * e;            // 0.5*erfc(ax)
    return (x >= 0.0f) ? (1.0f - h) : h;    // 0.5 + 0.5*erf(x)
}

// ws layout (doubles): [0..9] seg_reg, [10..19] seg_ce, [20..29] counts
__global__ __launch_bounds__(256) void aux_main(
    const int* __restrict__ yhat,
    const float* __restrict__ yg,
    const float* __restrict__ u_zg,
    double* __restrict__ ws)
{
    __shared__ float s_reg[C_CLS];
    __shared__ float s_ce[C_CLS];
    __shared__ float s_cnt[C_CLS];
    const int tid = threadIdx.x;
    if (tid < C_CLS) { s_reg[tid] = 0.f; s_ce[tid] = 0.f; s_cnt[tid] = 0.f; }
    __syncthreads();

    const int gtid = blockIdx.x * blockDim.x + tid;
    const int nthreads = gridDim.x * blockDim.x;
    const int lane = tid & 63;
    const int gwave = gtid >> 6;
    const int nwaves = nthreads >> 6;

    // ---- Phase A: u_zg erf regularizer; one wave handles 4 rows per iter ----
    const float4* __restrict__ u4 = (const float4*)u_zg;
    for (int g = gwave; g < (N_ROWS / 4); g += nwaves) {
        float4 v = u4[(size_t)g * 64 + lane];
        float t = f_reg(v.x) + f_reg(v.y) + f_reg(v.z) + f_reg(v.w);
        t += __shfl_xor(t, 1);
        t += __shfl_xor(t, 2);
        t += __shfl_xor(t, 4);
        t += __shfl_xor(t, 8);
        if ((lane & 15) == 0) {
            int row = g * 4 + (lane >> 4);
            atomicAdd(&s_reg[yhat[row]], t);
        }
    }

    // ---- Phase B: per-row cross entropy (10 classes, 40B rows, float2 loads) ----
    for (int row = gtid; row < N_ROWS; row += nthreads) {
        const float* __restrict__ yr = yg + (size_t)row * C_CLS;
        float2 a0 = *(const float2*)(yr + 0);
        float2 a1 = *(const float2*)(yr + 2);
        float2 a2 = *(const float2*)(yr + 4);
        float2 a3 = *(const float2*)(yr + 6);
        float2 a4 = *(const float2*)(yr + 8);
        float m = fmaxf(fmaxf(fmaxf(a0.x, a0.y), fmaxf(a1.x, a1.y)),
                 fmaxf(fmaxf(fmaxf(a2.x, a2.y), fmaxf(a3.x, a3.y)),
                       fmaxf(a4.x, a4.y)));
        float s = __expf(a0.x - m) + __expf(a0.y - m)
                + __expf(a1.x - m) + __expf(a1.y - m)
                + __expf(a2.x - m) + __expf(a2.y - m)
                + __expf(a3.x - m) + __expf(a3.y - m)
                + __expf(a4.x - m) + __expf(a4.y - m);
        float lse = m + __logf(s);
        int c = yhat[row];
        float ce = lse - yr[c];   // reload y[row,c]; L1 hit
        atomicAdd(&s_ce[c], ce);
        atomicAdd(&s_cnt[c], 1.0f);
    }

    __syncthreads();
    if (tid < C_CLS) {
        atomicAdd(&ws[tid],          (double)s_reg[tid]);
        atomicAdd(&ws[C_CLS + tid],  (double)s_ce[tid]);
        atomicAdd(&ws[2*C_CLS + tid],(double)s_cnt[tid]);
    }
}

__global__ void aux_final(const double* __restrict__ ws,
                          const float* __restrict__ lmbd,
                          float* __restrict__ out)
{
    if (threadIdx.x == 0 && blockIdx.x == 0) {
        double sreg = 0.0, sce = 0.0, nuniq = 0.0;
        for (int k = 0; k < C_CLS; ++k) {
            double cnt = ws[2*C_CLS + k];
            if (cnt > 0.0) {
                sreg += ws[k] / (cnt * (double)D_DIM);
                sce  += ws[C_CLS + k] / cnt;
                nuniq += 1.0;
            }
        }
        double reg_loss = sreg / nuniq;
        double aux_loss = sce / nuniq;
        out[0] = (float)(aux_loss + (double)lmbd[0] * reg_loss);
    }
}

extern "C" void kernel_launch(void* const* d_in, const int* in_sizes, int n_in,
                              void* d_out, int out_size, void* d_ws, size_t ws_size,
                              hipStream_t stream) {
    const int*   yhat = (const int*)d_in[0];
    const float* yg   = (const float*)d_in[1];
    const float* u_zg = (const float*)d_in[2];
    const float* lmbd = (const float*)d_in[3];
    float* out = (float*)d_out;
    double* ws = (double*)d_ws;

    hipMemsetAsync(ws, 0, 3 * C_CLS * sizeof(double), stream);
    aux_main<<<2048, 256, 0, stream>>>(yhat, yg, u_zg, ws);
    aux_final<<<1, 64, 0, stream>>>(ws, lmbd, out);
}

// Round 3
// 73.643 us; speedup vs baseline: 1.8947x; 1.7069x over previous
//
#include <hip/hip_runtime.h>
#include <math.h>

#define N_ROWS 1048576
#define C_CLS 10
#define D_DIM 64
#define NBLK 2048
#define NTHR 256
#define SLOT_STRIDE 32  // doubles per block slot (30 used)

// f(u) = 0.5 + 0.5*erf((u+0.5)*sqrt(2)); A&S 7.1.26, max abs err 1.5e-7
__device__ __forceinline__ float f_reg(float u) {
    float x  = fmaf(u, 1.41421356237f, 0.70710678118f);
    float ax = fabsf(x);
    float t  = __builtin_amdgcn_rcpf(fmaf(0.3275911f, ax, 1.0f));
    float p  = fmaf(fmaf(fmaf(fmaf(1.061405429f, t, -1.453152027f),
                              t, 1.421413741f),
                         t, -0.284496736f),
                    t, 0.254829592f);
    float e  = __expf(-ax * ax);
    float h  = 0.5f * p * t * e;            // 0.5*erfc(ax)
    return (x >= 0.0f) ? (1.0f - h) : h;
}

__device__ __forceinline__ float red16(float t) {
    t += __shfl_xor(t, 1);
    t += __shfl_xor(t, 2);
    t += __shfl_xor(t, 4);
    t += __shfl_xor(t, 8);
    return t;
}

__global__ __launch_bounds__(256) void aux_main(
    const int* __restrict__ yhat,
    const float* __restrict__ yg,
    const float* __restrict__ u_zg,
    double* __restrict__ ws)
{
    __shared__ float s_reg[C_CLS];
    __shared__ float s_ce[C_CLS];
    __shared__ float s_cnt[C_CLS];
    const int tid = threadIdx.x;
    if (tid < C_CLS) { s_reg[tid] = 0.f; s_ce[tid] = 0.f; s_cnt[tid] = 0.f; }
    __syncthreads();

    const int gtid = blockIdx.x * NTHR + tid;
    const int nthreads = NBLK * NTHR;
    const int lane = tid & 63;
    const int gwave = gtid >> 6;
    const int nwaves = nthreads >> 6;
    const int NG = N_ROWS / 4;
    const int sub = lane >> 4;

    // ---- Phase A: erf regularizer; wave handles 4 rows per group, 4 groups in flight ----
    const float4* __restrict__ u4 = (const float4*)u_zg;
    int g = gwave;
    for (; g + 3 * nwaves < NG; g += 4 * nwaves) {
        const int g1 = g + nwaves, g2 = g + 2 * nwaves, g3 = g + 3 * nwaves;
        float4 v0 = u4[(size_t)g  * 64 + lane];
        float4 v1 = u4[(size_t)g1 * 64 + lane];
        float4 v2 = u4[(size_t)g2 * 64 + lane];
        float4 v3 = u4[(size_t)g3 * 64 + lane];
        int c0 = yhat[g  * 4 + sub];
        int c1 = yhat[g1 * 4 + sub];
        int c2 = yhat[g2 * 4 + sub];
        int c3 = yhat[g3 * 4 + sub];
        float t0 = f_reg(v0.x) + f_reg(v0.y) + f_reg(v0.z) + f_reg(v0.w);
        float t1 = f_reg(v1.x) + f_reg(v1.y) + f_reg(v1.z) + f_reg(v1.w);
        float t2 = f_reg(v2.x) + f_reg(v2.y) + f_reg(v2.z) + f_reg(v2.w);
        float t3 = f_reg(v3.x) + f_reg(v3.y) + f_reg(v3.z) + f_reg(v3.w);
        t0 = red16(t0); t1 = red16(t1); t2 = red16(t2); t3 = red16(t3);
        if ((lane & 15) == 0) {
            atomicAdd(&s_reg[c0], t0);
            atomicAdd(&s_reg[c1], t1);
            atomicAdd(&s_reg[c2], t2);
            atomicAdd(&s_reg[c3], t3);
        }
    }
    for (; g < NG; g += nwaves) {
        float4 v = u4[(size_t)g * 64 + lane];
        int c = yhat[g * 4 + sub];
        float t = f_reg(v.x) + f_reg(v.y) + f_reg(v.z) + f_reg(v.w);
        t = red16(t);
        if ((lane & 15) == 0) atomicAdd(&s_reg[c], t);
    }

    // ---- Phase B: per-row CE, two rows fully interleaved for MLP ----
    {
        const int row0 = gtid;
        const int row1 = gtid + nthreads;
        const float* __restrict__ yr0 = yg + (size_t)row0 * C_CLS;
        const float* __restrict__ yr1 = yg + (size_t)row1 * C_CLS;
        float2 a0 = *(const float2*)(yr0 + 0);
        float2 a1 = *(const float2*)(yr0 + 2);
        float2 a2 = *(const float2*)(yr0 + 4);
        float2 a3 = *(const float2*)(yr0 + 6);
        float2 a4 = *(const float2*)(yr0 + 8);
        float2 b0 = *(const float2*)(yr1 + 0);
        float2 b1 = *(const float2*)(yr1 + 2);
        float2 b2 = *(const float2*)(yr1 + 4);
        float2 b3 = *(const float2*)(yr1 + 6);
        float2 b4 = *(const float2*)(yr1 + 8);
        int c0 = yhat[row0];
        int c1 = yhat[row1];
        float tgt0 = yr0[c0];
        float tgt1 = yr1[c1];

        float m0 = fmaxf(fmaxf(fmaxf(a0.x, a0.y), fmaxf(a1.x, a1.y)),
                  fmaxf(fmaxf(fmaxf(a2.x, a2.y), fmaxf(a3.x, a3.y)),
                        fmaxf(a4.x, a4.y)));
        float m1 = fmaxf(fmaxf(fmaxf(b0.x, b0.y), fmaxf(b1.x, b1.y)),
                  fmaxf(fmaxf(fmaxf(b2.x, b2.y), fmaxf(b3.x, b3.y)),
                        fmaxf(b4.x, b4.y)));
        float s0 = __expf(a0.x - m0) + __expf(a0.y - m0)
                 + __expf(a1.x - m0) + __expf(a1.y - m0)
                 + __expf(a2.x - m0) + __expf(a2.y - m0)
                 + __expf(a3.x - m0) + __expf(a3.y - m0)
                 + __expf(a4.x - m0) + __expf(a4.y - m0);
        float s1 = __expf(b0.x - m1) + __expf(b0.y - m1)
                 + __expf(b1.x - m1) + __expf(b1.y - m1)
                 + __expf(b2.x - m1) + __expf(b2.y - m1)
                 + __expf(b3.x - m1) + __expf(b3.y - m1)
                 + __expf(b4.x - m1) + __expf(b4.y - m1);
        float ce0 = m0 + __logf(s0) - tgt0;
        float ce1 = m1 + __logf(s1) - tgt1;
        atomicAdd(&s_ce[c0], ce0);
        atomicAdd(&s_ce[c1], ce1);
        atomicAdd(&s_cnt[c0], 1.0f);
        atomicAdd(&s_cnt[c1], 1.0f);
    }

    __syncthreads();
    // ---- per-block plain store of 30 partials (NO global atomics) ----
    if (tid < 3 * C_CLS) {
        float v = (tid < C_CLS) ? s_reg[tid]
                : (tid < 2 * C_CLS) ? s_ce[tid - C_CLS]
                : s_cnt[tid - 2 * C_CLS];
        ws[(size_t)blockIdx.x * SLOT_STRIDE + tid] = (double)v;
    }
}

__global__ __launch_bounds__(1024) void aux_final(
    const double* __restrict__ ws,
    const float* __restrict__ lmbd,
    float* __restrict__ out)
{
    __shared__ double s_part[32][33];
    __shared__ double s_tot[32];
    const int tid = threadIdx.x;     // 1024 threads
    const int e = tid & 31;          // entry 0..31 (30 used)
    const int c = tid >> 5;          // chunk 0..31, 64 blocks each
    double acc = 0.0;
    if (e < 3 * C_CLS) {
        for (int i = 0; i < NBLK / 32; ++i) {
            int b = c * (NBLK / 32) + i;
            acc += ws[(size_t)b * SLOT_STRIDE + e];
        }
    }
    s_part[c][e] = acc;
    __syncthreads();
    if (tid < 32) {
        double t = 0.0;
        for (int k = 0; k < 32; ++k) t += s_part[k][tid];
        s_tot[tid] = t;
    }
    __syncthreads();
    if (tid == 0) {
        double sreg = 0.0, sce = 0.0, nu = 0.0;
        for (int k = 0; k < C_CLS; ++k) {
            double cnt = s_tot[2 * C_CLS + k];
            if (cnt > 0.0) {
                sreg += s_tot[k] / (cnt * (double)D_DIM);
                sce  += s_tot[C_CLS + k] / cnt;
                nu += 1.0;
            }
        }
        out[0] = (float)(sce / nu + (double)lmbd[0] * (sreg / nu));
    }
}

extern "C" void kernel_launch(void* const* d_in, const int* in_sizes, int n_in,
                              void* d_out, int out_size, void* d_ws, size_t ws_size,
                              hipStream_t stream) {
    const int*   yhat = (const int*)d_in[0];
    const float* yg   = (const float*)d_in[1];
    const float* u_zg = (const float*)d_in[2];
    const float* lmbd = (const float*)d_in[3];
    float* out = (float*)d_out;
    double* ws = (double*)d_ws;

    aux_main<<<NBLK, NTHR, 0, stream>>>(yhat, yg, u_zg, ws);
    aux_final<<<1, 1024, 0, stream>>>(ws, lmbd, out);
}